// Round 2
// baseline (27989.206 us; speedup 1.0000x reference)
//
#include <hip/hip_runtime.h>

typedef __attribute__((ext_vector_type(8))) _Float16 half8;
typedef __attribute__((ext_vector_type(4))) float floatx4;

constexpr int T_STEPS = 1024, BATCH = 64, HID = 1024, NG = 4096, IN_DIM = 5;

// Workspace layout (bytes)
constexpr size_t O_W1H = 0;                                    // Whh0 fp16 [4096][1024]
constexpr size_t O_WC  = (size_t)NG * HID * 2;                 // [Wih1|Whh1] fp16 [4096][2048]
constexpr size_t O_BS0 = O_WC + (size_t)NG * 2 * HID * 2;      // bih0+bhh0 f32 [4096]
constexpr size_t O_BS1 = O_BS0 + NG * 4;                       // bih1+bhh1 f32 [4096]
constexpr size_t O_B1  = O_BS1 + NG * 4;                       // h1 ping-pong fp16 [2][64][1024]
constexpr size_t O_B2  = O_B1 + 2 * (size_t)BATCH * HID * 2;   // h2 ping-pong fp16 [2][64][1024]
constexpr size_t O_C1  = O_B2 + 2 * (size_t)BATCH * HID * 2;   // c1 f32 [64][1024]
constexpr size_t O_C2  = O_C1 + (size_t)BATCH * HID * 4;       // c2 f32 [64][1024]
constexpr size_t WS_NEEDED = O_C2 + (size_t)BATCH * HID * 4;

__device__ __forceinline__ float sigf(float x)   { return 1.f / (1.f + __expf(-x)); }
__device__ __forceinline__ float tanhft(float x) { return 2.f / (1.f + __expf(-2.f * x)) - 1.f; }
__device__ __forceinline__ floatx4 mfma16(half8 a, half8 b, floatx4 c) {
    return __builtin_amdgcn_mfma_f32_16x16x32_f16(a, b, c, 0, 0, 0);
}

// One-time (per call) weight convert + state init.
__global__ void prep_kernel(char* ws, const float* __restrict__ Whh0,
                            const float* __restrict__ Wih1, const float* __restrict__ Whh1,
                            const float* __restrict__ bih0, const float* __restrict__ bhh0,
                            const float* __restrict__ bih1, const float* __restrict__ bhh1)
{
    _Float16* W1h = (_Float16*)(ws + O_W1H);
    _Float16* Wc  = (_Float16*)(ws + O_WC);
    float* bs0 = (float*)(ws + O_BS0);
    float* bs1 = (float*)(ws + O_BS1);
    _Float16* hb = (_Float16*)(ws + O_B1);   // 4 * 64 * 1024 halves (buf1+buf2)
    float*    cb = (float*)(ws + O_C1);      // 2 * 64 * 1024 floats (c1+c2)
    int tid = blockIdx.x * blockDim.x + threadIdx.x;
    int stride = gridDim.x * blockDim.x;
    for (int i = tid; i < NG * HID; i += stride) W1h[i] = (_Float16)Whh0[i];
    for (int i = tid; i < NG * 2 * HID; i += stride) {
        int g = i >> 11, kk = i & 2047;
        float v = (kk < HID) ? Wih1[g * HID + kk] : Whh1[g * HID + kk - HID];
        Wc[i] = (_Float16)v;
    }
    for (int i = tid; i < NG; i += stride) { bs0[i] = bih0[i] + bhh0[i]; bs1[i] = bih1[i] + bhh1[i]; }
    for (int i = tid; i < 4 * BATCH * HID; i += stride) hb[i] = (_Float16)0.f;
    for (int i = tid; i < 2 * BATCH * HID; i += stride) cb[i] = 0.f;
}

// Wavefront step kernel k: layer1 step k, layer2 step k-1, out-projection step k-2.
// Buffer convention: h1[t] in buf1[t&1]; h2[t] in buf2[t&1].
__global__ void __launch_bounds__(256) step_kernel(
    int k, char* __restrict__ ws,
    const float* __restrict__ data, const int* __restrict__ lens,
    const float* __restrict__ Wih0, const float* __restrict__ Wout,
    const float* __restrict__ bout, float* __restrict__ out)
{
    const _Float16* W1h = (const _Float16*)(ws + O_W1H);
    const _Float16* Wc  = (const _Float16*)(ws + O_WC);
    const float* bs0 = (const float*)(ws + O_BS0);
    const float* bs1 = (const float*)(ws + O_BS1);
    _Float16* buf1 = (_Float16*)(ws + O_B1);
    _Float16* buf2 = (_Float16*)(ws + O_B2);
    float* c1 = (float*)(ws + O_C1);
    float* c2 = (float*)(ws + O_C2);

    const int bid  = blockIdx.x;
    const int tid  = threadIdx.x;
    const int lane = tid & 63;
    const int wv   = tid >> 6;
    const int lr   = lane & 15, lg = lane >> 4;

    if (bid < 64) {
        // ---------------- Layer 1, t = k ----------------
        if (k >= T_STEPS) return;
        const int t = k;
        const _Float16* hprev = buf1 + ((k + 1) & 1) * (BATCH * HID); // h1[k-1]
        _Float16*       hcur  = buf1 + (k & 1) * (BATCH * HID);       // h1[k]
        const int j0 = bid * 16;     // 16 hidden units
        const int mb = wv * 16;      // 16-batch slice per wave
        floatx4 acc0 = {0,0,0,0}, acc1 = {0,0,0,0}, acc2 = {0,0,0,0}, acc3 = {0,0,0,0};
        const _Float16* ap = hprev + (mb + lr) * HID + lg * 8;
        const _Float16* bp = W1h + (size_t)(j0 + lr) * HID + lg * 8;
        #pragma unroll 4
        for (int kk = 0; kk < HID; kk += 32) {
            half8 a = *(const half8*)(ap + kk);
            acc0 = mfma16(a, *(const half8*)(bp + kk), acc0);                   // i
            acc1 = mfma16(a, *(const half8*)(bp + 1 * HID * HID + kk), acc1);   // f
            acc2 = mfma16(a, *(const half8*)(bp + 2 * HID * HID + kk), acc2);   // g
            acc3 = mfma16(a, *(const half8*)(bp + 3 * HID * HID + kk), acc3);   // o
        }
        const int j = j0 + lr;
        float w0[5], w1[5], w2[5], w3[5];
        #pragma unroll
        for (int i = 0; i < IN_DIM; ++i) {
            w0[i] = Wih0[(0 * HID + j) * IN_DIM + i];
            w1[i] = Wih0[(1 * HID + j) * IN_DIM + i];
            w2[i] = Wih0[(2 * HID + j) * IN_DIM + i];
            w3[i] = Wih0[(3 * HID + j) * IN_DIM + i];
        }
        const float b0v = bs0[j], b1v = bs0[HID + j], b2v = bs0[2 * HID + j], b3v = bs0[3 * HID + j];
        #pragma unroll
        for (int r = 0; r < 4; ++r) {
            const int b = mb + lg * 4 + r;
            float gi = acc0[r] + b0v, gf = acc1[r] + b1v, gg = acc2[r] + b2v, go = acc3[r] + b3v;
            const float* xp = data + ((size_t)t * BATCH + b) * IN_DIM;
            #pragma unroll
            for (int i = 0; i < IN_DIM; ++i) {
                float xv = xp[i];
                gi += w0[i] * xv; gf += w1[i] * xv; gg += w2[i] * xv; go += w3[i] * xv;
            }
            const int off = b * HID + j;
            if (t < lens[b]) {
                float cold = c1[off];
                float cnew = sigf(gf) * cold + sigf(gi) * tanhft(gg);
                c1[off] = cnew;
                hcur[off] = (_Float16)(sigf(go) * tanhft(cnew));
            } else {
                hcur[off] = hprev[off];   // frozen state propagates
            }
        }
    } else if (bid < 192) {
        // ---------------- Layer 2, t = k-1 (gates = [Wih1|Whh1] @ [h1[t]; h2[t-1]]) ----------------
        if (k < 1 || k > T_STEPS) return;
        const int t = k - 1;
        const _Float16* h1p = buf1 + ((k + 1) & 1) * (BATCH * HID); // h1[k-1] = h1[t]
        const _Float16* h2p = buf2 + (k & 1) * (BATCH * HID);       // h2[t-1]
        _Float16*       h2c = buf2 + ((k + 1) & 1) * (BATCH * HID); // h2[t]
        const int idx = bid - 64;
        const int j0 = idx * 8;     // 8 hidden units
        const int mb = wv * 16;
        // tile0 columns: rows {i,f} x 8 units; tile1: rows {g,o} x 8 units
        const int row0 = ((lr >> 3) + 0) * HID + j0 + (lr & 7);
        const int row1 = ((lr >> 3) + 2) * HID + j0 + (lr & 7);
        floatx4 acc0 = {0,0,0,0}, acc1 = {0,0,0,0};
        const _Float16* b0 = Wc + (size_t)row0 * (2 * HID) + lg * 8;
        const _Float16* b1 = Wc + (size_t)row1 * (2 * HID) + lg * 8;
        const _Float16* a1 = h1p + (mb + lr) * HID + lg * 8;
        const _Float16* a2 = h2p + (mb + lr) * HID + lg * 8;
        #pragma unroll 4
        for (int kk = 0; kk < HID; kk += 32) {
            half8 a = *(const half8*)(a1 + kk);
            acc0 = mfma16(a, *(const half8*)(b0 + kk), acc0);
            acc1 = mfma16(a, *(const half8*)(b1 + kk), acc1);
        }
        #pragma unroll 4
        for (int kk = 0; kk < HID; kk += 32) {
            half8 a = *(const half8*)(a2 + kk);
            acc0 = mfma16(a, *(const half8*)(b0 + HID + kk), acc0);
            acc1 = mfma16(a, *(const half8*)(b1 + HID + kk), acc1);
        }
        const float base0 = bs1[row0], base1 = bs1[row1];
        #pragma unroll
        for (int r = 0; r < 4; ++r) {
            float v0 = acc0[r] + base0;       // lr<8: i-gate, else f-gate
            float v1 = acc1[r] + base1;       // lr<8: g-gate, else o-gate
            float p0 = __shfl_xor(v0, 8);     // partner's gate
            float p1 = __shfl_xor(v1, 8);
            if ((lr & 8) == 0) {
                const int j = j0 + (lr & 7);
                const int b = mb + lg * 4 + r;
                const int off = b * HID + j;
                if (t < lens[b]) {
                    float cold = c2[off];
                    float cnew = sigf(p0) * cold + sigf(v0) * tanhft(v1);
                    c2[off] = cnew;
                    h2c[off] = (_Float16)(sigf(p1) * tanhft(cnew));
                } else {
                    h2c[off] = h2p[off];
                }
            }
        }
    } else if (bid < 200) {
        // ---------------- Output projection + softmax, t = k-2 ----------------
        if (k < 2 || k > T_STEPS + 1) return;
        const int t = k - 2;
        const _Float16* h2 = buf2 + (k & 1) * (BATCH * HID);   // h2[t] = buf2[(k-2)&1]
        const int ow = bid - 192;
        #pragma unroll
        for (int s = 0; s < 2; ++s) {
            const int b = ow * 8 + wv * 2 + s;
            const bool valid = t < lens[b];
            float p0 = 0, p1 = 0, p2 = 0, p3 = 0, p4 = 0;
            if (valid) {   // wave-uniform branch (same b across wave)
                const _Float16* hp = h2 + b * HID;
                for (int ch = 0; ch < 16; ++ch) {
                    int j = ch * 64 + lane;
                    float hv = (float)hp[j];
                    p0 += hv * Wout[j];
                    p1 += hv * Wout[HID + j];
                    p2 += hv * Wout[2 * HID + j];
                    p3 += hv * Wout[3 * HID + j];
                    p4 += hv * Wout[4 * HID + j];
                }
                #pragma unroll
                for (int o = 32; o; o >>= 1) {
                    p0 += __shfl_xor(p0, o); p1 += __shfl_xor(p1, o);
                    p2 += __shfl_xor(p2, o); p3 += __shfl_xor(p3, o);
                    p4 += __shfl_xor(p4, o);
                }
            }
            if (lane == 0) {
                float l0 = p0 + bout[0], l1 = p1 + bout[1];
                float l2 = p2 + bout[2], l3 = p3 + bout[3], l4 = p4 + bout[4];
                float m  = fmaxf(l2, fmaxf(l3, l4));
                float e2 = __expf(l2 - m), e3 = __expf(l3 - m), e4 = __expf(l4 - m);
                float inv = 1.f / (e2 + e3 + e4);
                float* op = out + ((size_t)t * BATCH + b) * IN_DIM;
                op[0] = l0; op[1] = l1; op[2] = e2 * inv; op[3] = e3 * inv; op[4] = e4 * inv;
            }
        }
    }
}

extern "C" void kernel_launch(void* const* d_in, const int* in_sizes, int n_in,
                              void* d_out, int out_size, void* d_ws, size_t ws_size,
                              hipStream_t stream)
{
    if (ws_size < WS_NEEDED) return;   // refuse to scribble OOB — fail clean, not crash

    const float* data = (const float*)d_in[0];
    const int*   lens = (const int*)d_in[1];
    const float* Wih0 = (const float*)d_in[2];
    const float* Whh0 = (const float*)d_in[3];
    const float* bih0 = (const float*)d_in[4];
    const float* bhh0 = (const float*)d_in[5];
    const float* Wih1 = (const float*)d_in[6];   // Wih_rest[0]
    const float* Whh1 = (const float*)d_in[7];   // Whh_rest[0]
    const float* bih1 = (const float*)d_in[8];
    const float* bhh1 = (const float*)d_in[9];
    const float* Wout = (const float*)d_in[10];
    const float* bout = (const float*)d_in[11];
    char* ws = (char*)d_ws;

    prep_kernel<<<256, 256, 0, stream>>>(ws, Whh0, Wih1, Whh1, bih0, bhh0, bih1, bhh1);
    for (int k = 0; k <= T_STEPS + 1; ++k) {
        step_kernel<<<200, 256, 0, stream>>>(k, ws, data, lens, Wih0, Wout, bout, (float*)d_out);
    }
}